// Round 1
// baseline (2340.325 us; speedup 1.0000x reference)
//
#include <hip/hip_runtime.h>
#include <float.h>

// Problem constants (fixed by the reference).
#define NUM_CELLS 2048
#define CELL_DIM  256
#define N_STATES  131072

// Tiling.
#define BM 64          // states per block
#define BN 64          // cells per tile
#define BK 32          // k-chunk for p staging
#define XP 260         // x LDS pitch in floats (256 + 4 pad: row start bank += 4)
#define PP 68          // p^T LDS pitch in floats (64 + 4 pad, keeps 16B align)

// LDS budget: x tile 64*260*4 = 66560 B, p^T tile 32*68*4 = 8704 B -> 75264 B
// => 2 blocks/CU (150.5 KiB <= 160 KiB), 8 waves/CU.

__launch_bounds__(256, 2)
__global__ void placecells_argmax_fp32(const float* __restrict__ x,
                                       const float* __restrict__ pc,
                                       int* __restrict__ out) {
    __shared__ float xs[BM * XP];
    __shared__ float ps[BK * PP];   // reused as reduction buffer at the end

    const int tid = threadIdx.x;
    const int tx = tid & 15;        // cell group (16 groups x 4 cells = 64)
    const int ty = tid >> 4;        // state group (16 groups x 4 states = 64)

    // ---- Stage x tile: 64 states x 256 k, coalesced float4 loads ----
    const float* xg = x + (size_t)blockIdx.x * (BM * CELL_DIM);
#pragma unroll
    for (int i = 0; i < 16; ++i) {
        int f  = tid + i * 256;          // float4 index 0..4095
        int s  = f >> 6;                 // 64 float4 per row
        int k4 = (f & 63) << 2;
        float4 v = *(const float4*)(xg + s * CELL_DIM + k4);
        *(float4*)(&xs[s * XP + k4]) = v;
    }
    __syncthreads();

    // Running argmax state: 4 states per thread, over this thread's cell columns.
    float runv[4];
    int   runi[4];
#pragma unroll
    for (int si = 0; si < 4; ++si) { runv[si] = -FLT_MAX; runi[si] = 0; }

    for (int jc = 0; jc < NUM_CELLS; jc += BN) {
        float acc[4][4];
#pragma unroll
        for (int si = 0; si < 4; ++si)
#pragma unroll
            for (int cj = 0; cj < 4; ++cj) acc[si][cj] = 0.0f;

        for (int kc = 0; kc < CELL_DIM; kc += BK) {
            __syncthreads();   // protect ps from previous chunk's readers
            // ---- Stage p chunk transposed: ps[k_local][c], 64 cells x 32 k ----
#pragma unroll
            for (int i = 0; i < 2; ++i) {
                int f  = tid + i * 256;        // float4 index 0..511
                int c  = f >> 3;               // 8 float4 per (cell,chunk) row
                int k4 = (f & 7) << 2;
                float4 v = *(const float4*)(pc + (size_t)(jc + c) * CELL_DIM + kc + k4);
                ps[(k4 + 0) * PP + c] = v.x;
                ps[(k4 + 1) * PP + c] = v.y;
                ps[(k4 + 2) * PP + c] = v.z;
                ps[(k4 + 3) * PP + c] = v.w;
            }
            __syncthreads();

            // ---- Compute: 4 states x 4 cells microtile over BK ----
#pragma unroll
            for (int kk = 0; kk < BK; kk += 4) {
                float4 xv[4];
#pragma unroll
                for (int si = 0; si < 4; ++si)
                    xv[si] = *(const float4*)(&xs[(ty * 4 + si) * XP + kc + kk]);
#pragma unroll
                for (int kt = 0; kt < 4; ++kt) {
                    float4 pv = *(const float4*)(&ps[(kk + kt) * PP + tx * 4]);
#pragma unroll
                    for (int si = 0; si < 4; ++si) {
                        float xk = (kt == 0) ? xv[si].x :
                                   (kt == 1) ? xv[si].y :
                                   (kt == 2) ? xv[si].z : xv[si].w;
                        acc[si][0] = fmaf(xk, pv.x, acc[si][0]);
                        acc[si][1] = fmaf(xk, pv.y, acc[si][1]);
                        acc[si][2] = fmaf(xk, pv.z, acc[si][2]);
                        acc[si][3] = fmaf(xk, pv.w, acc[si][3]);
                    }
                }
            }
        }

        // ---- Update running argmax (strict > keeps earliest index) ----
#pragma unroll
        for (int si = 0; si < 4; ++si) {
#pragma unroll
            for (int cj = 0; cj < 4; ++cj) {
                int idx = jc + tx * 4 + cj;
                if (acc[si][cj] > runv[si]) { runv[si] = acc[si][cj]; runi[si] = idx; }
            }
        }
    }

    // ---- Cross-thread (tx) reduction per state, tie -> smaller index ----
    __syncthreads();                       // everyone done reading ps
    float* rv = ps;                        // 1024 floats
    int*   ri = (int*)(ps + 1024);         // 1024 ints (ps has 2176 floats)
#pragma unroll
    for (int si = 0; si < 4; ++si) {
        int s = ty * 4 + si;
        rv[s * 16 + tx] = runv[si];
        ri[s * 16 + tx] = runi[si];
    }
    __syncthreads();
    if (tid < BM) {
        int s = tid;
        float bv = rv[s * 16 + 0];
        int   bi = ri[s * 16 + 0];
#pragma unroll
        for (int t = 1; t < 16; ++t) {
            float v = rv[s * 16 + t];
            int   i = ri[s * 16 + t];
            if (v > bv || (v == bv && i < bi)) { bv = v; bi = i; }
        }
        out[(size_t)blockIdx.x * BM + s] = bi;
    }
}

extern "C" void kernel_launch(void* const* d_in, const int* in_sizes, int n_in,
                              void* d_out, int out_size, void* d_ws, size_t ws_size,
                              hipStream_t stream) {
    const float* x  = (const float*)d_in[0];   // (131072, 256) fp32
    const float* pc = (const float*)d_in[1];   // (2048, 256) fp32
    int* out = (int*)d_out;                    // (131072,) int32 argmax indices

    dim3 grid(N_STATES / BM);   // 2048 blocks
    dim3 block(256);
    placecells_argmax_fp32<<<grid, block, 0, stream>>>(x, pc, out);
}

// Round 2
// 747.388 us; speedup vs baseline: 3.1313x; 3.1313x over previous
//
#include <hip/hip_runtime.h>
#include <float.h>
#include <stdint.h>

#define NUM_CELLS 2048
#define CELL_DIM  256
#define N_STATES  131072

typedef _Float16 half8  __attribute__((ext_vector_type(8)));
typedef _Float16 half4v __attribute__((ext_vector_type(4)));
typedef float    f32x16 __attribute__((ext_vector_type(16)));

// Ambiguity margin: fp16x2 sim noise sigma ~2e-5; top-2 gap mean ~4.1.
// 0.004 = ~100 sigma safety; expected flagged rows ~130 (trivial rescue cost).
#define MARGIN 0.004f

// Workspace layout (bytes)
#define WS_LIST_OFF 1024
#define WS_PH_OFF   1048576
#define WS_PL_OFF   2097152
#define WS_NEEDED   3145728

// ---------------------------------------------------------------------------
// Prep: split placeCells fp32 -> (hi, lo) fp16 arrays in ws; zero rescue count.
// ---------------------------------------------------------------------------
__global__ void prep_kernel(const float* __restrict__ p, _Float16* __restrict__ ph,
                            _Float16* __restrict__ pl, int* __restrict__ count) {
    int i = (blockIdx.x * 256 + threadIdx.x) * 4;
    if (i == 0) *count = 0;
    float4 v = *(const float4*)(p + i);
    half4v h, lo;
    h.x = (_Float16)v.x; lo.x = (_Float16)(v.x - (float)h.x);
    h.y = (_Float16)v.y; lo.y = (_Float16)(v.y - (float)h.y);
    h.z = (_Float16)v.z; lo.z = (_Float16)(v.z - (float)h.z);
    h.w = (_Float16)v.w; lo.w = (_Float16)(v.w - (float)h.w);
    *(half4v*)(ph + i) = h;
    *(half4v*)(pl + i) = lo;
}

// ---------------------------------------------------------------------------
// Kernel A: fp16x2 MFMA GEMM + per-row running top-2 + flag ambiguous rows.
// Block = 128 rows x all 2048 cells (8 tiles of 256). 512 threads = 8 waves
// in 2(row)x4(col); wave tile 64x64 = 2x2 of 32x32x16 MFMAs.
// LDS frag-order layout: frag base + lane*16B -> zero bank conflicts.
// ---------------------------------------------------------------------------
__launch_bounds__(512, 2)
__global__ void placecells_mfma(const float* __restrict__ x,
                                const _Float16* __restrict__ ph,
                                const _Float16* __restrict__ pl,
                                int* __restrict__ out,
                                int* __restrict__ wcount,
                                int* __restrict__ wlist) {
    __shared__ _Float16 xs_hi[4096];   // (rt0..3, ks0..1, half, m) * 8 halves
    __shared__ _Float16 xs_lo[4096];
    __shared__ _Float16 ps_hi[8192];   // (ct0..7, ks0..1, half, m) * 8 halves
    __shared__ _Float16 ps_lo[8192];

    const int tid = threadIdx.x;
    const int l   = tid & 63;
    const int w   = tid >> 6;
    const int wr  = w >> 2;    // 0..1: row group (64 rows)
    const int wc  = w & 3;     // 0..3: col group (64 cols)

    const float* xg = x + (size_t)blockIdx.x * (128 * CELL_DIM);

    // staging unit assignment
    const int xrow = tid >> 2, xgrp = tid & 3;           // x: (row, 8-float group)
    const int pc0  = tid >> 2, pg0 = tid & 3;            // ps unit, iter 0
    const int pc1  = (tid + 512) >> 2, pg1 = (tid + 512) & 3;

    float4 xa, xb;
    half8 pa_h, pa_l, pb_h, pb_l;

    auto preload = [&](int n) {
        const int kc = (n & 7) * 32;
        const int jc = (n >> 3) * 256;
        const float* xp = xg + xrow * CELL_DIM + kc + xgrp * 8;
        xa = *(const float4*)xp;
        xb = *(const float4*)(xp + 4);
        int o0 = (jc + pc0) * CELL_DIM + kc + pg0 * 8;
        pa_h = *(const half8*)(ph + o0);
        pa_l = *(const half8*)(pl + o0);
        int o1 = (jc + pc1) * CELL_DIM + kc + pg1 * 8;
        pb_h = *(const half8*)(ph + o1);
        pb_l = *(const half8*)(pl + o1);
    };

    auto commit = [&]() {
        float vv[8] = {xa.x, xa.y, xa.z, xa.w, xb.x, xb.y, xb.z, xb.w};
        half8 hv, lv;
#pragma unroll
        for (int j = 0; j < 8; ++j) {
            _Float16 h = (_Float16)vv[j];
            hv[j] = h;
            lv[j] = (_Float16)(vv[j] - (float)h);
        }
        {   int rt = xrow >> 5, m = xrow & 31, ks = xgrp >> 1, hf = xgrp & 1;
            int d = (rt * 2 + ks) * 512 + (hf * 32 + m) * 8;
            *(half8*)(xs_hi + d) = hv;
            *(half8*)(xs_lo + d) = lv; }
        {   int ct = pc0 >> 5, m = pc0 & 31, ks = pg0 >> 1, hf = pg0 & 1;
            int d = (ct * 2 + ks) * 512 + (hf * 32 + m) * 8;
            *(half8*)(ps_hi + d) = pa_h;
            *(half8*)(ps_lo + d) = pa_l; }
        {   int ct = pc1 >> 5, m = pc1 & 31, ks = pg1 >> 1, hf = pg1 & 1;
            int d = (ct * 2 + ks) * 512 + (hf * 32 + m) * 8;
            *(half8*)(ps_hi + d) = pb_h;
            *(half8*)(ps_lo + d) = pb_l; }
    };

    // running top-2 per (lane, row-slot): slot = rti*16 + reg
    float t1[32], t2[32]; int i1[32];
#pragma unroll
    for (int s = 0; s < 32; ++s) { t1[s] = -FLT_MAX; t2[s] = -FLT_MAX; i1[s] = 0; }

    preload(0);
    for (int jc = 0; jc < 8; ++jc) {
        f32x16 acc00 = {}, acc01 = {}, acc10 = {}, acc11 = {};
        for (int kb = 0; kb < 8; ++kb) {
            __syncthreads();           // previous chunk's frag reads done
            commit();
            __syncthreads();           // LDS staged
            int n = jc * 8 + kb + 1;
            if (n < 64) preload(n);    // globals fly under the MFMA work
#pragma unroll
            for (int ks = 0; ks < 2; ++ks) {
                const int lb = l * 8;
                half8 Ah0 = *(const half8*)(xs_hi + (wr * 4 + 0 + ks) * 512 + lb);
                half8 Ah1 = *(const half8*)(xs_hi + (wr * 4 + 2 + ks) * 512 + lb);
                half8 Al0 = *(const half8*)(xs_lo + (wr * 4 + 0 + ks) * 512 + lb);
                half8 Al1 = *(const half8*)(xs_lo + (wr * 4 + 2 + ks) * 512 + lb);
                half8 Bh0 = *(const half8*)(ps_hi + (wc * 4 + 0 + ks) * 512 + lb);
                half8 Bh1 = *(const half8*)(ps_hi + (wc * 4 + 2 + ks) * 512 + lb);
                half8 Bl0 = *(const half8*)(ps_lo + (wc * 4 + 0 + ks) * 512 + lb);
                half8 Bl1 = *(const half8*)(ps_lo + (wc * 4 + 2 + ks) * 512 + lb);
                acc00 = __builtin_amdgcn_mfma_f32_32x32x16_f16(Ah0, Bh0, acc00, 0, 0, 0);
                acc01 = __builtin_amdgcn_mfma_f32_32x32x16_f16(Ah0, Bh1, acc01, 0, 0, 0);
                acc10 = __builtin_amdgcn_mfma_f32_32x32x16_f16(Ah1, Bh0, acc10, 0, 0, 0);
                acc11 = __builtin_amdgcn_mfma_f32_32x32x16_f16(Ah1, Bh1, acc11, 0, 0, 0);
                acc00 = __builtin_amdgcn_mfma_f32_32x32x16_f16(Ah0, Bl0, acc00, 0, 0, 0);
                acc01 = __builtin_amdgcn_mfma_f32_32x32x16_f16(Ah0, Bl1, acc01, 0, 0, 0);
                acc10 = __builtin_amdgcn_mfma_f32_32x32x16_f16(Ah1, Bl0, acc10, 0, 0, 0);
                acc11 = __builtin_amdgcn_mfma_f32_32x32x16_f16(Ah1, Bl1, acc11, 0, 0, 0);
                acc00 = __builtin_amdgcn_mfma_f32_32x32x16_f16(Al0, Bh0, acc00, 0, 0, 0);
                acc01 = __builtin_amdgcn_mfma_f32_32x32x16_f16(Al0, Bh1, acc01, 0, 0, 0);
                acc10 = __builtin_amdgcn_mfma_f32_32x32x16_f16(Al1, Bh0, acc10, 0, 0, 0);
                acc11 = __builtin_amdgcn_mfma_f32_32x32x16_f16(Al1, Bh1, acc11, 0, 0, 0);
            }
        }
        // epilogue: fold this 256-cell tile into running top-2
#define UPD(ACC, RTI, CT2)                                                    \
        {   int idx = jc * 256 + (wc * 2 + (CT2)) * 32 + (l & 31);            \
            _Pragma("unroll")                                                 \
            for (int reg = 0; reg < 16; ++reg) {                              \
                int s = (RTI) * 16 + reg;                                     \
                float v = (ACC)[reg];                                         \
                float nt2 = __builtin_amdgcn_fmed3f(t1[s], t2[s], v);         \
                bool g = v > t1[s];                                           \
                i1[s] = g ? idx : i1[s];                                      \
                t1[s] = fmaxf(t1[s], v);                                      \
                t2[s] = nt2;                                                  \
            }                                                                 \
        }
        UPD(acc00, 0, 0) UPD(acc01, 0, 1) UPD(acc10, 1, 0) UPD(acc11, 1, 1)
#undef UPD
    }

    // cross-lane butterfly over the 32 column lanes (stays within lane>>5 halves)
#pragma unroll
    for (int mi = 0; mi < 5; ++mi) {
        const int msk = 1 << mi;
#pragma unroll
        for (int s = 0; s < 32; ++s) {
            float ot1 = __shfl_xor(t1[s], msk, 64);
            int   oi1 = __shfl_xor(i1[s], msk, 64);
            float ot2 = __shfl_xor(t2[s], msk, 64);
            float nt2 = fmaxf(fminf(t1[s], ot1), fmaxf(t2[s], ot2));
            if (ot1 > t1[s]) { t1[s] = ot1; i1[s] = oi1; }
            t2[s] = nt2;
        }
    }

    __syncthreads();   // main loop fully done; reuse ps_hi as reduction buffer
    float* rT1 = (float*)ps_hi;          // 512 floats (4 col groups x 128 rows)
    int*   rI1 = (int*)ps_hi + 512;
    float* rT2 = (float*)ps_hi + 1024;
    if ((l & 31) == 0) {
#pragma unroll
        for (int s = 0; s < 32; ++s) {
            int rti = s >> 4, reg = s & 15;
            int row = wr * 64 + rti * 32 + (reg & 3) + 8 * (reg >> 2) + 4 * (l >> 5);
            rT1[wc * 128 + row] = t1[s];
            rI1[wc * 128 + row] = i1[s];
            rT2[wc * 128 + row] = t2[s];
        }
    }
    __syncthreads();
    if (tid < 128) {
        float T1 = -FLT_MAX, T2 = -FLT_MAX; int I1 = 0;
#pragma unroll
        for (int g = 0; g < 4; ++g) {
            float a1 = rT1[g * 128 + tid];
            int   ai = rI1[g * 128 + tid];
            float a2 = rT2[g * 128 + tid];
            float nt2 = fmaxf(fminf(T1, a1), fmaxf(T2, a2));
            if (a1 > T1 || (a1 == T1 && ai < I1)) { T1 = a1; I1 = ai; }
            T2 = nt2;
        }
        int grow = blockIdx.x * 128 + tid;
        out[grow] = I1;
        if (T1 - T2 < MARGIN) {
            int pos = atomicAdd(wcount, 1);
            wlist[pos] = grow;
        }
    }
}

// ---------------------------------------------------------------------------
// Kernel B: exact fp32 argmax for flagged rows (expected ~130 total).
// numpy-compatible tie-break: first (smallest) index on exact equality.
// ---------------------------------------------------------------------------
__global__ void rescue_kernel(const float* __restrict__ x, const float* __restrict__ p,
                              const int* __restrict__ count, const int* __restrict__ list,
                              int* __restrict__ out) {
    __shared__ float xrow[256];
    __shared__ float pch[32][260];
    __shared__ float red2[32][9];
    __shared__ float bvs[32];
    __shared__ int   bis[32];
    const int tid = threadIdx.x;
    const int n = *count;
    for (int e = blockIdx.x; e < n; e += gridDim.x) {
        const int row = list[e];
        __syncthreads();
        if (tid < 64) {
            float4 v = *(const float4*)(x + (size_t)row * 256 + tid * 4);
            *(float4*)(&xrow[tid * 4]) = v;
        }
        float bv = -FLT_MAX; int bi = 0;
        const int cell = tid & 31, kq = tid >> 5;   // 8 k-quarters of 32
        for (int c0 = 0; c0 < NUM_CELLS; c0 += 32) {
            __syncthreads();
            // stage 32 cells x 256 k, coalesced
#pragma unroll
            for (int i = 0; i < 8; ++i) {
                int f = tid + i * 256;
                int cr = f >> 6, k4 = (f & 63) * 4;
                float4 v = *(const float4*)(p + (size_t)(c0 + cr) * 256 + k4);
                *(float4*)(&pch[cr][k4]) = v;
            }
            __syncthreads();
            float s = 0.f;
#pragma unroll
            for (int j = 0; j < 8; ++j) {
                float4 pv = *(const float4*)(&pch[cell][kq * 32 + j * 4]);
                float4 xv = *(const float4*)(&xrow[kq * 32 + j * 4]);
                s = fmaf(xv.x, pv.x, s); s = fmaf(xv.y, pv.y, s);
                s = fmaf(xv.z, pv.z, s); s = fmaf(xv.w, pv.w, s);
            }
            red2[cell][kq] = s;
            __syncthreads();
            if (tid < 32) {
                float dot = 0.f;
#pragma unroll
                for (int q = 0; q < 8; ++q) dot += red2[tid][q];
                if (dot > bv) { bv = dot; bi = c0 + tid; }
            }
        }
        if (tid < 32) { bvs[tid] = bv; bis[tid] = bi; }
        __syncthreads();
        if (tid == 0) {
            float B = bvs[0]; int BI = bis[0];
#pragma unroll
            for (int t = 1; t < 32; ++t) {
                if (bvs[t] > B || (bvs[t] == B && bis[t] < BI)) { B = bvs[t]; BI = bis[t]; }
            }
            out[row] = BI;
        }
    }
}

// ---------------------------------------------------------------------------
// Fallback (round-1 kernel): correct fp32 vector path if ws is too small.
// ---------------------------------------------------------------------------
#define BM 64
#define BN 64
#define BK 32
#define XP 260
#define PP 68
__launch_bounds__(256, 2)
__global__ void placecells_argmax_fp32(const float* __restrict__ x,
                                       const float* __restrict__ pc,
                                       int* __restrict__ out) {
    __shared__ float xs[BM * XP];
    __shared__ float ps[BK * PP];
    const int tid = threadIdx.x;
    const int tx = tid & 15;
    const int ty = tid >> 4;
    const float* xg = x + (size_t)blockIdx.x * (BM * CELL_DIM);
#pragma unroll
    for (int i = 0; i < 16; ++i) {
        int f = tid + i * 256;
        int s = f >> 6, k4 = (f & 63) << 2;
        *(float4*)(&xs[s * XP + k4]) = *(const float4*)(xg + s * CELL_DIM + k4);
    }
    __syncthreads();
    float runv[4]; int runi[4];
#pragma unroll
    for (int si = 0; si < 4; ++si) { runv[si] = -FLT_MAX; runi[si] = 0; }
    for (int jc = 0; jc < NUM_CELLS; jc += BN) {
        float acc[4][4];
#pragma unroll
        for (int si = 0; si < 4; ++si)
#pragma unroll
            for (int cj = 0; cj < 4; ++cj) acc[si][cj] = 0.0f;
        for (int kc = 0; kc < CELL_DIM; kc += BK) {
            __syncthreads();
#pragma unroll
            for (int i = 0; i < 2; ++i) {
                int f = tid + i * 256;
                int c = f >> 3, k4 = (f & 7) << 2;
                float4 v = *(const float4*)(pc + (size_t)(jc + c) * CELL_DIM + kc + k4);
                ps[(k4 + 0) * PP + c] = v.x; ps[(k4 + 1) * PP + c] = v.y;
                ps[(k4 + 2) * PP + c] = v.z; ps[(k4 + 3) * PP + c] = v.w;
            }
            __syncthreads();
#pragma unroll
            for (int kk = 0; kk < BK; kk += 4) {
                float4 xv[4];
#pragma unroll
                for (int si = 0; si < 4; ++si)
                    xv[si] = *(const float4*)(&xs[(ty * 4 + si) * XP + kc + kk]);
#pragma unroll
                for (int kt = 0; kt < 4; ++kt) {
                    float4 pv = *(const float4*)(&ps[(kk + kt) * PP + tx * 4]);
#pragma unroll
                    for (int si = 0; si < 4; ++si) {
                        float xk = (kt == 0) ? xv[si].x : (kt == 1) ? xv[si].y :
                                   (kt == 2) ? xv[si].z : xv[si].w;
                        acc[si][0] = fmaf(xk, pv.x, acc[si][0]);
                        acc[si][1] = fmaf(xk, pv.y, acc[si][1]);
                        acc[si][2] = fmaf(xk, pv.z, acc[si][2]);
                        acc[si][3] = fmaf(xk, pv.w, acc[si][3]);
                    }
                }
            }
        }
#pragma unroll
        for (int si = 0; si < 4; ++si)
#pragma unroll
            for (int cj = 0; cj < 4; ++cj) {
                int idx = jc + tx * 4 + cj;
                if (acc[si][cj] > runv[si]) { runv[si] = acc[si][cj]; runi[si] = idx; }
            }
    }
    __syncthreads();
    float* rv = ps; int* ri = (int*)(ps + 1024);
#pragma unroll
    for (int si = 0; si < 4; ++si) {
        int s = ty * 4 + si;
        rv[s * 16 + tx] = runv[si]; ri[s * 16 + tx] = runi[si];
    }
    __syncthreads();
    if (tid < BM) {
        float bv = rv[tid * 16]; int bi = ri[tid * 16];
#pragma unroll
        for (int t = 1; t < 16; ++t) {
            float v = rv[tid * 16 + t]; int i = ri[tid * 16 + t];
            if (v > bv || (v == bv && i < bi)) { bv = v; bi = i; }
        }
        out[(size_t)blockIdx.x * BM + tid] = bi;
    }
}

extern "C" void kernel_launch(void* const* d_in, const int* in_sizes, int n_in,
                              void* d_out, int out_size, void* d_ws, size_t ws_size,
                              hipStream_t stream) {
    const float* x  = (const float*)d_in[0];   // (131072, 256) fp32
    const float* pc = (const float*)d_in[1];   // (2048, 256) fp32
    int* out = (int*)d_out;

    if (ws_size >= (size_t)WS_NEEDED) {
        char* ws = (char*)d_ws;
        int* wcount = (int*)ws;
        int* wlist  = (int*)(ws + WS_LIST_OFF);
        _Float16* ph = (_Float16*)(ws + WS_PH_OFF);
        _Float16* pl = (_Float16*)(ws + WS_PL_OFF);
        prep_kernel<<<512, 256, 0, stream>>>(pc, ph, pl, wcount);
        placecells_mfma<<<N_STATES / 128, 512, 0, stream>>>(x, ph, pl, out, wcount, wlist);
        rescue_kernel<<<128, 256, 0, stream>>>(x, pc, wcount, wlist, out);
    } else {
        placecells_argmax_fp32<<<N_STATES / BM, 256, 0, stream>>>(x, pc, out);
    }
}

// Round 3
// 505.128 us; speedup vs baseline: 4.6331x; 1.4796x over previous
//
#include <hip/hip_runtime.h>
#include <float.h>
#include <stdint.h>

#define NUM_CELLS 2048
#define CELL_DIM  256
#define N_STATES  131072

typedef _Float16 half8 __attribute__((ext_vector_type(8)));
typedef float    f32x4 __attribute__((ext_vector_type(4)));

// Stage-1 (1-pass fp16) sim-difference noise sigma ~6.4e-3; M1 = 15.6 sigma.
#define M1 0.10f
// Stage-2 (fp16x2 3-pass) noise sigma ~2e-5; M2 = 200 sigma.
#define M2 0.004f
#define CAP1 32768
#define CAP2 4096

// ws layout (bytes). Round-2 confirmed ws_size >= 3145728.
#define WS_C1 0
#define WS_C2 4
#define WS_L1 1024
#define WS_L2 (1024 + 4 * CAP1)
#define WS_PH 262144
#define WS_PL (262144 + 1048576)
#define WS_NEEDED (WS_PL + 1048576)   // 2359296

__device__ __forceinline__ void gld_lds16(const void* g, void* l) {
    __builtin_amdgcn_global_load_lds(
        (const __attribute__((address_space(1))) void*)g,
        (__attribute__((address_space(3))) void*)l, 16, 0, 0);
}

// ---------------------------------------------------------------------------
// Prep: p fp32 -> B-fragment-order fp16 hi + (lo*2048) arrays; zero counters.
// Frag order (16x16x32 f16 B): half8 index d = (ct*8 + kf)*64 + l, where
// cell = ct*16 + (l&15), k = kf*32 + (l>>4)*8 + j.
// ---------------------------------------------------------------------------
__global__ void prep_p(const float* __restrict__ p, _Float16* __restrict__ ph,
                       _Float16* __restrict__ pl, int* __restrict__ c1,
                       int* __restrict__ c2) {
    int d = blockIdx.x * 256 + threadIdx.x;   // 65536 dests
    if (d == 0) { *c1 = 0; *c2 = 0; }
    int l = d & 63, kf = (d >> 6) & 7, ct = d >> 9;
    int cell = ct * 16 + (l & 15);
    int k0 = kf * 32 + (l >> 4) * 8;
    const float* s = p + cell * 256 + k0;
    float4 a = *(const float4*)s, b = *(const float4*)(s + 4);
    float v[8] = {a.x, a.y, a.z, a.w, b.x, b.y, b.z, b.w};
    half8 h, lo;
#pragma unroll
    for (int j = 0; j < 8; ++j) {
        _Float16 hi = (_Float16)v[j];
        h[j] = hi;
        lo[j] = (_Float16)((v[j] - (float)hi) * 2048.0f);  // scaled: avoid fp16 denorms
    }
    *(half8*)(ph + (size_t)d * 8) = h;
    *(half8*)(pl + (size_t)d * 8) = lo;
}

// ---------------------------------------------------------------------------
// Kernel A: 1-pass fp16 MFMA GEMM + running top-2 + margin flag.
// Block = 128 rows x 2048 cells; 512 thr = 8 waves (wr 0..1 x wc 0..3).
// A-frags (own 64 rows, full K) live in 128 VGPRs; B double-buffered via
// global_load_lds from frag-order ph; 64-cell chunks, 1 barrier per chunk.
// ---------------------------------------------------------------------------
__launch_bounds__(512, 2)
__global__ void pc_gemm1(const float* __restrict__ x, const _Float16* __restrict__ ph,
                         int* __restrict__ out, int* __restrict__ c1,
                         int* __restrict__ l1) {
    __shared__ _Float16 smem[32768];   // 64 KB; pb0 = smem, pb1 = smem + 16384

    const int tid = threadIdx.x;
    const int l = tid & 63;
    const int w = tid >> 6;
    const int wr = w >> 2, wc = w & 3;

    // Phase 1: x fp32 -> fp16 A-frag order in LDS (once per block).
    const float* xg = x + (size_t)blockIdx.x * (128 * CELL_DIM);
#pragma unroll
    for (int i = 0; i < 8; ++i) {
        int d = tid + i * 512;            // 4096 half8 dests
        int dl = d & 63, kf = (d >> 6) & 7, rt = d >> 9;
        int row = rt * 16 + (dl & 15);
        int k0 = kf * 32 + (dl >> 4) * 8;
        const float* s = xg + row * 256 + k0;
        float4 a = *(const float4*)s, b = *(const float4*)(s + 4);
        half8 h;
        h[0] = (_Float16)a.x; h[1] = (_Float16)a.y;
        h[2] = (_Float16)a.z; h[3] = (_Float16)a.w;
        h[4] = (_Float16)b.x; h[5] = (_Float16)b.y;
        h[6] = (_Float16)b.z; h[7] = (_Float16)b.w;
        *(half8*)(smem + d * 8) = h;
    }
    __syncthreads();

    // A-frags to registers: own 64 rows (tiles wr*4 .. wr*4+3), full K.
    half8 A[4][8];
#pragma unroll
    for (int rt = 0; rt < 4; ++rt)
#pragma unroll
        for (int kf = 0; kf < 8; ++kf)
            A[rt][kf] = *(const half8*)(smem + (((wr * 4 + rt) * 8 + kf) * 64 + l) * 8);
    __syncthreads();   // xs dead; LDS becomes p double-buffer

    const char* pbase = (const char*)ph;
    auto stage = [&](int c) {
        char* dst = (char*)smem + (c & 1) * 32768;
        const char* src = pbase + (size_t)c * 32768;   // 64 cells x 256 k fp16
#pragma unroll
        for (int i = 0; i < 4; ++i) {
            int off = w * 4096 + i * 1024;
            gld_lds16(src + off + l * 16, dst + off);
        }
    };

    float t1[16], t2[16];
    int ic[16];
#pragma unroll
    for (int s = 0; s < 16; ++s) { t1[s] = -FLT_MAX; t2[s] = -FLT_MAX; ic[s] = 0; }

    stage(0);
    __syncthreads();   // drain stage(0)

    for (int c = 0; c < 32; ++c) {
        if (c < 31) stage(c + 1);   // flies under this chunk's MFMAs
        const _Float16* pb = smem + (c & 1) * 16384 + wc * 4096;
        f32x4 a0 = {}, a1 = {}, a2 = {}, a3 = {};
#pragma unroll
        for (int kf = 0; kf < 8; ++kf) {
            half8 B = *(const half8*)(pb + kf * 512 + l * 8);
            a0 = __builtin_amdgcn_mfma_f32_16x16x32_f16(A[0][kf], B, a0, 0, 0, 0);
            a1 = __builtin_amdgcn_mfma_f32_16x16x32_f16(A[1][kf], B, a1, 0, 0, 0);
            a2 = __builtin_amdgcn_mfma_f32_16x16x32_f16(A[2][kf], B, a2, 0, 0, 0);
            a3 = __builtin_amdgcn_mfma_f32_16x16x32_f16(A[3][kf], B, a3, 0, 0, 0);
        }
#define UPD(ACC, RT)                                                       \
        _Pragma("unroll")                                                  \
        for (int reg = 0; reg < 4; ++reg) {                                \
            int s = (RT) * 4 + reg;                                        \
            float v = (ACC)[reg];                                          \
            float nt2 = __builtin_amdgcn_fmed3f(t1[s], t2[s], v);          \
            ic[s] = (v > t1[s]) ? c : ic[s];                               \
            t1[s] = fmaxf(t1[s], v);                                       \
            t2[s] = nt2;                                                   \
        }
        UPD(a0, 0) UPD(a1, 1) UPD(a2, 2) UPD(a3, 3)
#undef UPD
        __syncthreads();
    }

    // Butterfly across the 16 column lanes (masks < 16 keep l>>4 fixed).
    int idx[16];
#pragma unroll
    for (int s = 0; s < 16; ++s) idx[s] = ic[s] * 64 + wc * 16 + (l & 15);
#pragma unroll
    for (int m = 1; m <= 8; m <<= 1) {
#pragma unroll
        for (int s = 0; s < 16; ++s) {
            float ot1 = __shfl_xor(t1[s], m, 64);
            int   oi  = __shfl_xor(idx[s], m, 64);
            float ot2 = __shfl_xor(t2[s], m, 64);
            float nt2 = fmaxf(fminf(t1[s], ot1), fmaxf(t2[s], ot2));
            if (ot1 > t1[s] || (ot1 == t1[s] && oi < idx[s])) { t1[s] = ot1; idx[s] = oi; }
            t2[s] = nt2;
        }
    }

    // Per-wave partials -> LDS (last loop barrier already passed).
    float* rT1 = (float*)smem;          // 512
    int*   rI1 = (int*)smem + 512;
    float* rT2 = (float*)smem + 1024;
    if ((l & 15) == 0) {
#pragma unroll
        for (int rt = 0; rt < 4; ++rt)
#pragma unroll
            for (int reg = 0; reg < 4; ++reg) {
                int s = rt * 4 + reg;
                int row = wr * 64 + rt * 16 + (l >> 4) * 4 + reg;
                rT1[row * 4 + wc] = t1[s];
                rI1[row * 4 + wc] = idx[s];
                rT2[row * 4 + wc] = t2[s];
            }
    }
    __syncthreads();
    if (tid < 128) {
        float T1 = -FLT_MAX, T2 = -FLT_MAX; int I1 = 0x7FFFFFFF;
#pragma unroll
        for (int g = 0; g < 4; ++g) {
            float v1 = rT1[tid * 4 + g];
            int   vi = rI1[tid * 4 + g];
            float v2 = rT2[tid * 4 + g];
            float nt2 = fmaxf(fminf(T1, v1), fmaxf(T2, v2));
            if (v1 > T1 || (v1 == T1 && vi < I1)) { T1 = v1; I1 = vi; }
            T2 = nt2;
        }
        int grow = blockIdx.x * 128 + tid;
        out[grow] = I1;
        if (T1 - T2 < M1) {
            int pos = atomicAdd(c1, 1);
            if (pos < CAP1) l1[pos] = grow;
        }
    }
}

// ---------------------------------------------------------------------------
// Kernel B: fp16x2 3-pass MFMA on flagged rows (gathered). Block = 32 rows,
// 256 thr = 4 waves (wr = row tile, wc = cell tile of 32-cell chunk).
// A hi/lo built in-registers from fp32 x; B from frag-order ph/pl (lo x2048).
// ---------------------------------------------------------------------------
__launch_bounds__(256, 2)
__global__ void pc_rescue2(const float* __restrict__ x, const _Float16* __restrict__ ph,
                           const _Float16* __restrict__ pl,
                           const int* __restrict__ c1, const int* __restrict__ l1,
                           int* __restrict__ out, int* __restrict__ c2,
                           int* __restrict__ l2) {
    __shared__ _Float16 sB[32768];   // 64 KB: 2 bufs x (hi 8192 | lo 8192 halves)
    const int n = *c1;
    const int base = blockIdx.x * 32;
    if (base >= n) return;
    const int tid = threadIdx.x;
    const int l = tid & 63, w = tid >> 6;
    const int wr = w >> 1, wc = w & 1;

    const int rslot = base + wr * 16 + (l & 15);
    const int my_row = l1[rslot < n ? rslot : (n - 1)];

    half8 Ah[8], Al[8];
#pragma unroll
    for (int kf = 0; kf < 8; ++kf) {
        const float* s = x + (size_t)my_row * 256 + kf * 32 + (l >> 4) * 8;
        float4 a = *(const float4*)s, b = *(const float4*)(s + 4);
        float v[8] = {a.x, a.y, a.z, a.w, b.x, b.y, b.z, b.w};
#pragma unroll
        for (int j = 0; j < 8; ++j) {
            _Float16 hi = (_Float16)v[j];
            Ah[kf][j] = hi;
            Al[kf][j] = (_Float16)((v[j] - (float)hi) * 2048.0f);
        }
    }

    auto stageB = [&](int c) {
        char* dst = (char*)sB + (c & 1) * 32768;
        const char* sh = (const char*)ph + (size_t)c * 16384;  // 32 cells x 256 k
        const char* sl = (const char*)pl + (size_t)c * 16384;
#pragma unroll
        for (int i = 0; i < 4; ++i) {
            int off = w * 4096 + i * 1024;
            gld_lds16(sh + off + l * 16, dst + off);
            gld_lds16(sl + off + l * 16, dst + 16384 + off);
        }
    };

    float t1[4], t2[4];
    int ic[4];
#pragma unroll
    for (int s = 0; s < 4; ++s) { t1[s] = -FLT_MAX; t2[s] = -FLT_MAX; ic[s] = 0; }

    stageB(0);
    __syncthreads();
    for (int c = 0; c < 64; ++c) {
        if (c < 63) stageB(c + 1);
        const _Float16* bh = sB + (c & 1) * 16384 + wc * 4096;
        const _Float16* bl = bh + 8192;
        f32x4 hh = {}, hl = {}, lh = {};
#pragma unroll
        for (int kf = 0; kf < 8; ++kf) {
            half8 Bh = *(const half8*)(bh + kf * 512 + l * 8);
            half8 Bl = *(const half8*)(bl + kf * 512 + l * 8);
            hh = __builtin_amdgcn_mfma_f32_16x16x32_f16(Ah[kf], Bh, hh, 0, 0, 0);
            hl = __builtin_amdgcn_mfma_f32_16x16x32_f16(Ah[kf], Bl, hl, 0, 0, 0);
            lh = __builtin_amdgcn_mfma_f32_16x16x32_f16(Al[kf], Bh, lh, 0, 0, 0);
        }
#pragma unroll
        for (int reg = 0; reg < 4; ++reg) {
            float v = hh[reg] + (hl[reg] + lh[reg]) * (1.0f / 2048.0f);
            float nt2 = __builtin_amdgcn_fmed3f(t1[reg], t2[reg], v);
            ic[reg] = (v > t1[reg]) ? c : ic[reg];
            t1[reg] = fmaxf(t1[reg], v);
            t2[reg] = nt2;
        }
        __syncthreads();
    }

    int idx[4];
#pragma unroll
    for (int s = 0; s < 4; ++s) idx[s] = ic[s] * 32 + wc * 16 + (l & 15);
#pragma unroll
    for (int m = 1; m <= 8; m <<= 1) {
#pragma unroll
        for (int s = 0; s < 4; ++s) {
            float ot1 = __shfl_xor(t1[s], m, 64);
            int   oi  = __shfl_xor(idx[s], m, 64);
            float ot2 = __shfl_xor(t2[s], m, 64);
            float nt2 = fmaxf(fminf(t1[s], ot1), fmaxf(t2[s], ot2));
            if (ot1 > t1[s] || (ot1 == t1[s] && oi < idx[s])) { t1[s] = ot1; idx[s] = oi; }
            t2[s] = nt2;
        }
    }

    float* rT1 = (float*)sB;           // 64
    int*   rI1 = (int*)sB + 64;
    float* rT2 = (float*)sB + 128;
    if ((l & 15) == 0) {
#pragma unroll
        for (int reg = 0; reg < 4; ++reg) {
            int row = wr * 16 + (l >> 4) * 4 + reg;
            rT1[row * 2 + wc] = t1[reg];
            rI1[row * 2 + wc] = idx[reg];
            rT2[row * 2 + wc] = t2[reg];
        }
    }
    __syncthreads();
    if (tid < 32) {
        float T1 = -FLT_MAX, T2 = -FLT_MAX; int I1 = 0x7FFFFFFF;
#pragma unroll
        for (int g = 0; g < 2; ++g) {
            float v1 = rT1[tid * 2 + g];
            int   vi = rI1[tid * 2 + g];
            float v2 = rT2[tid * 2 + g];
            float nt2 = fmaxf(fminf(T1, v1), fmaxf(T2, v2));
            if (v1 > T1 || (v1 == T1 && vi < I1)) { T1 = v1; I1 = vi; }
            T2 = nt2;
        }
        int slot = base + tid;
        if (slot < n) {
            int grow = l1[slot];
            out[grow] = I1;
            if (T1 - T2 < M2) {
                int pos = atomicAdd(c2, 1);
                if (pos < CAP2) l2[pos] = grow;
            }
        }
    }
}

// ---------------------------------------------------------------------------
// Kernel C: exact fp32 argmax for residual rows (expected ~3).
// ---------------------------------------------------------------------------
__global__ void rescue3(const float* __restrict__ x, const float* __restrict__ p,
                        const int* __restrict__ count, const int* __restrict__ list,
                        int* __restrict__ out) {
    __shared__ float xrow[256];
    __shared__ float pch[32][260];
    __shared__ float red2[32][9];
    __shared__ float bvs[32];
    __shared__ int   bis[32];
    const int tid = threadIdx.x;
    const int n = *count;
    for (int e = blockIdx.x; e < n; e += gridDim.x) {
        const int row = list[e];
        __syncthreads();
        if (tid < 64) {
            float4 v = *(const float4*)(x + (size_t)row * 256 + tid * 4);
            *(float4*)(&xrow[tid * 4]) = v;
        }
        float bv = -FLT_MAX; int bi = 0;
        const int cell = tid & 31, kq = tid >> 5;
        for (int c0 = 0; c0 < NUM_CELLS; c0 += 32) {
            __syncthreads();
#pragma unroll
            for (int i = 0; i < 8; ++i) {
                int f = tid + i * 256;
                int cr = f >> 6, k4 = (f & 63) * 4;
                float4 v = *(const float4*)(p + (size_t)(c0 + cr) * 256 + k4);
                *(float4*)(&pch[cr][k4]) = v;
            }
            __syncthreads();
            float s = 0.f;
#pragma unroll
            for (int j = 0; j < 8; ++j) {
                float4 pv = *(const float4*)(&pch[cell][kq * 32 + j * 4]);
                float4 xv = *(const float4*)(&xrow[kq * 32 + j * 4]);
                s = fmaf(xv.x, pv.x, s); s = fmaf(xv.y, pv.y, s);
                s = fmaf(xv.z, pv.z, s); s = fmaf(xv.w, pv.w, s);
            }
            red2[cell][kq] = s;
            __syncthreads();
            if (tid < 32) {
                float dot = 0.f;
#pragma unroll
                for (int q = 0; q < 8; ++q) dot += red2[tid][q];
                if (dot > bv) { bv = dot; bi = c0 + tid; }
            }
        }
        if (tid < 32) { bvs[tid] = bv; bis[tid] = bi; }
        __syncthreads();
        if (tid == 0) {
            float B = bvs[0]; int BI = bis[0];
#pragma unroll
            for (int t = 1; t < 32; ++t)
                if (bvs[t] > B || (bvs[t] == B && bis[t] < BI)) { B = bvs[t]; BI = bis[t]; }
            out[row] = BI;
        }
    }
}

// ---------------------------------------------------------------------------
// Fallback (round-1 fp32 vector path) if ws too small.
// ---------------------------------------------------------------------------
#define BM 64
#define BN 64
#define BK 32
#define XP 260
#define PP 68
__launch_bounds__(256, 2)
__global__ void placecells_argmax_fp32(const float* __restrict__ x,
                                       const float* __restrict__ pc,
                                       int* __restrict__ out) {
    __shared__ float xs[BM * XP];
    __shared__ float ps[BK * PP];
    const int tid = threadIdx.x;
    const int tx = tid & 15;
    const int ty = tid >> 4;
    const float* xg = x + (size_t)blockIdx.x * (BM * CELL_DIM);
#pragma unroll
    for (int i = 0; i < 16; ++i) {
        int f = tid + i * 256;
        int s = f >> 6, k4 = (f & 63) << 2;
        *(float4*)(&xs[s * XP + k4]) = *(const float4*)(xg + s * CELL_DIM + k4);
    }
    __syncthreads();
    float runv[4]; int runi[4];
#pragma unroll
    for (int si = 0; si < 4; ++si) { runv[si] = -FLT_MAX; runi[si] = 0; }
    for (int jc = 0; jc < NUM_CELLS; jc += BN) {
        float acc[4][4];
#pragma unroll
        for (int si = 0; si < 4; ++si)
#pragma unroll
            for (int cj = 0; cj < 4; ++cj) acc[si][cj] = 0.0f;
        for (int kc = 0; kc < CELL_DIM; kc += BK) {
            __syncthreads();
#pragma unroll
            for (int i = 0; i < 2; ++i) {
                int f = tid + i * 256;
                int c = f >> 3, k4 = (f & 7) << 2;
                float4 v = *(const float4*)(pc + (size_t)(jc + c) * CELL_DIM + kc + k4);
                ps[(k4 + 0) * PP + c] = v.x; ps[(k4 + 1) * PP + c] = v.y;
                ps[(k4 + 2) * PP + c] = v.z; ps[(k4 + 3) * PP + c] = v.w;
            }
            __syncthreads();
#pragma unroll
            for (int kk = 0; kk < BK; kk += 4) {
                float4 xv[4];
#pragma unroll
                for (int si = 0; si < 4; ++si)
                    xv[si] = *(const float4*)(&xs[(ty * 4 + si) * XP + kc + kk]);
#pragma unroll
                for (int kt = 0; kt < 4; ++kt) {
                    float4 pv = *(const float4*)(&ps[(kk + kt) * PP + tx * 4]);
#pragma unroll
                    for (int si = 0; si < 4; ++si) {
                        float xk = (kt == 0) ? xv[si].x : (kt == 1) ? xv[si].y :
                                   (kt == 2) ? xv[si].z : xv[si].w;
                        acc[si][0] = fmaf(xk, pv.x, acc[si][0]);
                        acc[si][1] = fmaf(xk, pv.y, acc[si][1]);
                        acc[si][2] = fmaf(xk, pv.z, acc[si][2]);
                        acc[si][3] = fmaf(xk, pv.w, acc[si][3]);
                    }
                }
            }
        }
#pragma unroll
        for (int si = 0; si < 4; ++si)
#pragma unroll
            for (int cj = 0; cj < 4; ++cj) {
                int idx = jc + tx * 4 + cj;
                if (acc[si][cj] > runv[si]) { runv[si] = acc[si][cj]; runi[si] = idx; }
            }
    }
    __syncthreads();
    float* rv = ps; int* ri = (int*)(ps + 1024);
#pragma unroll
    for (int si = 0; si < 4; ++si) {
        int s = ty * 4 + si;
        rv[s * 16 + tx] = runv[si]; ri[s * 16 + tx] = runi[si];
    }
    __syncthreads();
    if (tid < BM) {
        float bv = rv[tid * 16]; int bi = ri[tid * 16];
#pragma unroll
        for (int t = 1; t < 16; ++t) {
            float v = rv[tid * 16 + t]; int i = ri[tid * 16 + t];
            if (v > bv || (v == bv && i < bi)) { bv = v; bi = i; }
        }
        out[(size_t)blockIdx.x * BM + tid] = bi;
    }
}

extern "C" void kernel_launch(void* const* d_in, const int* in_sizes, int n_in,
                              void* d_out, int out_size, void* d_ws, size_t ws_size,
                              hipStream_t stream) {
    const float* x  = (const float*)d_in[0];   // (131072, 256) fp32
    const float* pc = (const float*)d_in[1];   // (2048, 256) fp32
    int* out = (int*)d_out;

    if (ws_size >= (size_t)WS_NEEDED) {
        char* ws = (char*)d_ws;
        int* c1 = (int*)(ws + WS_C1);
        int* c2 = (int*)(ws + WS_C2);
        int* l1 = (int*)(ws + WS_L1);
        int* l2 = (int*)(ws + WS_L2);
        _Float16* ph = (_Float16*)(ws + WS_PH);
        _Float16* pl = (_Float16*)(ws + WS_PL);
        prep_p<<<256, 256, 0, stream>>>(pc, ph, pl, c1, c2);
        pc_gemm1<<<N_STATES / 128, 512, 0, stream>>>(x, ph, out, c1, l1);
        pc_rescue2<<<CAP1 / 32, 256, 0, stream>>>(x, ph, pl, c1, l1, out, c2, l2);
        rescue3<<<64, 256, 0, stream>>>(x, pc, c2, l2, out);
    } else {
        placecells_argmax_fp32<<<N_STATES / BM, 256, 0, stream>>>(x, pc, out);
    }
}